// Round 11
// baseline (268.005 us; speedup 1.0000x reference)
//
#include <hip/hip_runtime.h>

#define BLOCK 256
#define NB 5      // objects per scene
#define DD 12     // per-object feature dim
#define EE 64     // goal embedding dim
#define HH 32     // F1 hidden dim
#define ROW 81    // D + E + N
#define OUTW 405  // N * ROW
#define TILE 64   // rows per block in assemble kernel
#define SPW 12    // scenes per wave (5 lanes each, lanes 60-63 idle)
#define SPB 48    // scenes per block (4 waves)
#define W1P 28    // padded W1^T row stride
#define BBS 84    // s_bb scene stride (5*16 + 4 pad: bank-spread, 16B aligned)
#define G2P 36    // s_g2 scene stride (32 + 4 pad)

// ---------------- kernel A: compute zhat[B,5], 5 threads per scene ----------------
// lane = s*5 + j. Thread computes a[16],bb[16] for one 16-h half; bb exchanged
// ONCE per half via LDS (broadcast b128 reads); g2 exchanged once via LDS.
// No per-h shuffles. Softmax via ~10-shfl group reduce (proven R10 epilogue).
__global__ __launch_bounds__(BLOCK) void zhat_kernel(
    const float* __restrict__ obs, const float* __restrict__ ghat,
    const float* __restrict__ W1, const float* __restrict__ b1,
    const float* __restrict__ W2, const float* __restrict__ b2,
    float* __restrict__ zbuf, int zstride, int zoff, int B)
{
    __shared__ float s_W1t[HH * W1P];   // W1^T [h][d<24], uniform broadcast reads
    __shared__ float s_b1[HH];
    __shared__ float s_w2s[HH];         // rowsum(W2)
    __shared__ float s_sb2;             // sum(b2)
    __shared__ float s_bb[SPB * BBS];   // bb exchange: [scene][j][16]
    __shared__ float s_g2[SPB * G2P];   // g2 exchange: [scene][32]

    const int tid = threadIdx.x;

    // ---- stage W1^T (coalesced read, linearized write), b1, w2s, sb2 ----
    for (int idx = tid; idx < 2 * DD * HH; idx += BLOCK) {
        const int h = idx & (HH - 1);       // idx = d*32 + h
        const int d = idx >> 5;
        s_W1t[h * W1P + d] = W1[idx];
    }
    if (tid < HH) {
        s_b1[tid] = b1[tid];
        float s = 0.f;
        const float4* p = reinterpret_cast<const float4*>(W2 + tid * EE);
        #pragma unroll
        for (int q = 0; q < EE / 4; ++q) { float4 v = p[q]; s += (v.x + v.y) + (v.z + v.w); }
        s_w2s[tid] = s;
    } else if (tid == HH) {
        float s = 0.f;
        #pragma unroll
        for (int e = 0; e < EE; ++e) s += b2[e];
        s_sb2 = s;
    }

    const int lane  = tid & 63;
    const int wv    = tid >> 6;
    const int sIn   = lane / 5;               // scene within wave (12 => idle lane)
    const int j     = lane - sIn * 5;         // my object row
    const int base5 = sIn * 5;                // first lane of my 5-lane group
    const bool on   = (sIn < SPW);
    const int sBlk  = on ? (wv * SPW + sIn) : 0;   // LDS scene slot (clamped)
    const int i     = blockIdx.x * SPB + wv * SPW + sIn;
    const bool act  = on && (i < B);
    const int ic    = act ? i : (B - 1);      // clamp loads; stores guarded

    // ---- my obs row (12 floats; group of 5 lanes covers 60 contiguous) ----
    float o[DD];
    {
        const float4* p = reinterpret_cast<const float4*>(obs + (size_t)ic * (NB * DD) + j * DD);
        #pragma unroll
        for (int q = 0; q < 3; ++q) {
            float4 v = p[q];
            o[4*q+0] = v.x; o[4*q+1] = v.y; o[4*q+2] = v.z; o[4*q+3] = v.w;
        }
    }

    // ---- GEMV for owned h's (h%16 == j+5*hp), both halves; park in s_g2 ----
    {
        float g2own[8];
        #pragma unroll
        for (int q = 0; q < 8; ++q) g2own[q] = 0.f;
        const float* grow = ghat + (size_t)ic * EE;
        #pragma unroll 1
        for (int ec = 0; ec < 4; ++ec) {          // 16 e per chunk
            float gc[16];
            const float4* gp = reinterpret_cast<const float4*>(grow + ec * 16);
            #pragma unroll
            for (int q = 0; q < 4; ++q) {
                float4 v = gp[q];
                gc[4*q+0] = v.x; gc[4*q+1] = v.y; gc[4*q+2] = v.z; gc[4*q+3] = v.w;
            }
            #pragma unroll
            for (int q = 0; q < 8; ++q) {
                const int hl = j + 5 * (q & 3);   // h within half
                if (hl < 16) {                    // exec-masked tail
                    const float4* wp = reinterpret_cast<const float4*>(
                        W2 + ((q >> 2) * 16 + hl) * EE + ec * 16);   // L1-hot (8KB)
                    #pragma unroll
                    for (int qv = 0; qv < 4; ++qv) {
                        float4 wvv = wp[qv];
                        g2own[q] += (gc[4*qv+0] * wvv.x + gc[4*qv+1] * wvv.y)
                                  + (gc[4*qv+2] * wvv.z + gc[4*qv+3] * wvv.w);
                    }
                }
            }
        }
        if (on) {
            #pragma unroll
            for (int q = 0; q < 8; ++q) {
                const int hl = j + 5 * (q & 3);
                if (hl < 16)
                    s_g2[sBlk * G2P + (q >> 2) * 16 + hl] = g2own[q];
            }
        }
    }
    __syncthreads();   // staging + g2 exchange complete

    float w[NB], hw[NB];
    #pragma unroll
    for (int k = 0; k < NB; ++k) { w[k] = 0.f; hw[k] = 0.f; }

    #pragma unroll 1
    for (int half = 0; half < 2; ++half) {
        // ---- a/bb for my row over this half's 16 h (LDS broadcast W1 reads) ----
        float a[16], bb[16];
        #pragma unroll
        for (int hl = 0; hl < 16; ++hl) {
            const int h = half * 16 + hl;         // uniform across block
            const float* w1r = &s_W1t[h * W1P];
            float av = s_b1[h], bv = 0.f;
            #pragma unroll
            for (int dc = 0; dc < 3; ++dc) {
                const float4 wt = *reinterpret_cast<const float4*>(w1r + dc * 4);
                const float4 wb = *reinterpret_cast<const float4*>(w1r + DD + dc * 4);
                av += (o[4*dc+0] * wt.x + o[4*dc+1] * wt.y)
                    + (o[4*dc+2] * wt.z + o[4*dc+3] * wt.w);
                bv += (o[4*dc+0] * wb.x + o[4*dc+1] * wb.y)
                    + (o[4*dc+2] * wb.z + o[4*dc+3] * wb.w);
            }
            a[hl] = av; bb[hl] = bv;
        }
        __syncthreads();   // previous half's s_bb reads are done
        if (on) {
            float4* dst = reinterpret_cast<float4*>(&s_bb[sBlk * BBS + j * 16]);
            #pragma unroll
            for (int c = 0; c < 4; ++c)
                dst[c] = make_float4(bb[4*c+0], bb[4*c+1], bb[4*c+2], bb[4*c+3]);
        }
        __syncthreads();   // s_bb ready for this half

        // ---- accumulate w,hw: 2 chunks of 8 h, b128 broadcast reads ----
        #pragma unroll
        for (int c2 = 0; c2 < 2; ++c2) {
            const int hb = half * 16 + c2 * 8;
            float g2c[8], w2c[8];
            {
                const float4* gp = reinterpret_cast<const float4*>(&s_g2[sBlk * G2P + hb]);
                const float4 v0 = gp[0], v1 = gp[1];
                g2c[0]=v0.x; g2c[1]=v0.y; g2c[2]=v0.z; g2c[3]=v0.w;
                g2c[4]=v1.x; g2c[5]=v1.y; g2c[6]=v1.z; g2c[7]=v1.w;
                const float4* up = reinterpret_cast<const float4*>(&s_w2s[hb]);
                const float4 u0 = up[0], u1 = up[1];
                w2c[0]=u0.x; w2c[1]=u0.y; w2c[2]=u0.z; w2c[3]=u0.w;
                w2c[4]=u1.x; w2c[5]=u1.y; w2c[6]=u1.z; w2c[7]=u1.w;
            }
            #pragma unroll
            for (int k = 0; k < NB; ++k) {
                const float4* bp = reinterpret_cast<const float4*>(
                    &s_bb[sBlk * BBS + k * 16 + c2 * 8]);
                const float4 b0 = bp[0], b1v = bp[1];
                const float bl[8] = {b0.x, b0.y, b0.z, b0.w, b1v.x, b1v.y, b1v.z, b1v.w};
                #pragma unroll
                for (int e = 0; e < 8; ++e) {
                    const float hv = fmaxf(a[c2*8 + e] + bl[e], 0.f);
                    w[k]  += hv * g2c[e];
                    hw[k] += hv * w2c[e];
                }
            }
        }
    }

    // ---- softmax across the 5-lane group (epilogue: ~10 shfls total) ----
    float mrow = w[0];
    #pragma unroll
    for (int k = 1; k < NB; ++k) mrow = fmaxf(mrow, w[k]);
    float m = mrow;
    #pragma unroll
    for (int k = 0; k < NB; ++k) m = fmaxf(m, __shfl(mrow, base5 + k));

    float r = 0.f, z = 0.f;
    #pragma unroll
    for (int k = 0; k < NB; ++k) {
        const float ev = __expf(w[k] - m);
        r += ev;
        z += ev * hw[k];
    }
    float l = 0.f;
    #pragma unroll
    for (int k = 0; k < NB; ++k) l += __shfl(r, base5 + k);

    if (act) {
        zbuf[(size_t)i * zstride + zoff + j] = (z + s_sb2 * r) / l;
    }
}

// ---------------- kernel B: assemble output (proven R3 path) ----------------
__global__ __launch_bounds__(BLOCK) void assemble_kernel(
    const float* __restrict__ obs, const float* __restrict__ ghat,
    const float* __restrict__ zbuf, int zstride, int zoff,
    float* __restrict__ out, int B)
{
    __shared__ float s_obs[TILE * NB * DD];  // 3840 floats
    __shared__ float s_gh[TILE * EE];        // 4096 floats
    __shared__ float s_zh[TILE * NB];        // 320 floats

    const int tid = threadIdx.x;
    const int r0 = blockIdx.x * TILE;
    const int rows = (B - r0 < TILE) ? (B - r0) : TILE;

    for (int t = tid; t < rows * NB * DD; t += BLOCK)
        s_obs[t] = obs[(size_t)r0 * NB * DD + t];
    for (int t = tid; t < rows * EE; t += BLOCK)
        s_gh[t] = ghat[(size_t)r0 * EE + t];
    for (int t = tid; t < rows * NB; t += BLOCK) {
        const int row = t / NB, k = t - row * NB;
        s_zh[t] = zbuf[(size_t)(r0 + row) * zstride + zoff + k];
    }
    __syncthreads();

    const size_t base = (size_t)r0 * OUTW;
    for (int t = tid; t < rows * OUTW; t += BLOCK) {
        const int il = t / OUTW;
        const int r  = t - il * OUTW;
        const int j  = r / ROW;
        const int rr = r - j * ROW;
        float v;
        if (rr < DD)           v = s_obs[il * NB * DD + j * DD + rr];
        else if (rr < DD + EE) v = s_gh[il * EE + (rr - DD)];
        else                   v = s_zh[il * NB + (rr - (DD + EE))];
        out[base + t] = v;
    }
}

extern "C" void kernel_launch(void* const* d_in, const int* in_sizes, int n_in,
                              void* d_out, int out_size, void* d_ws, size_t ws_size,
                              hipStream_t stream) {
    const float* obs  = (const float*)d_in[0];
    const float* ghat = (const float*)d_in[1];
    const float* W1   = (const float*)d_in[2];
    const float* b1   = (const float*)d_in[3];
    const float* W2   = (const float*)d_in[4];
    const float* b2   = (const float*)d_in[5];
    float* out = (float*)d_out;

    const int B = in_sizes[0] / (NB * DD);

    // zhat scratch: d_ws if large enough, else stash in last 5 floats of each
    // output row (assemble reads its tile's stash before overwriting it).
    float* zbuf; int zstride, zoff;
    if (ws_size >= (size_t)B * NB * sizeof(float)) {
        zbuf = (float*)d_ws; zstride = NB;   zoff = 0;
    } else {
        zbuf = out;          zstride = OUTW; zoff = OUTW - NB;
    }

    const int gridA = (B + SPB - 1) / SPB;
    hipLaunchKernelGGL(zhat_kernel, dim3(gridA), dim3(BLOCK), 0, stream,
                       obs, ghat, W1, b1, W2, b2, zbuf, zstride, zoff, B);

    const int gridB = (B + TILE - 1) / TILE;
    hipLaunchKernelGGL(assemble_kernel, dim3(gridB), dim3(BLOCK), 0, stream,
                       obs, ghat, zbuf, zstride, zoff, out, B);
}

// Round 12
// 235.748 us; speedup vs baseline: 1.1368x; 1.1368x over previous
//
#include <hip/hip_runtime.h>

#define BLOCK 256
#define NB 5      // objects per scene
#define DD 12     // per-object feature dim
#define EE 64     // goal embedding dim
#define HH 32     // F1 hidden dim
#define ROW 81    // D + E + N
#define OUTW 405  // N * ROW
#define TILE 64   // rows per block in assemble kernel
#define S8 8      // scenes per block in zhat kernel
#define ABS 36    // s_ab row stride (32 + 4: bank-spread, 144B = 16B-aligned)
#define G2S 36    // s_g2 scene stride

// ---------------- kernel A: compute zhat[B,5] ----------------
// 32 threads per scene, 8 scenes per block. Three phases, all through LDS:
//  P1a: thread owns h=t&31, computes 10 a/b dot-products -> s_ab[scene][row][h]
//  P1b: thread (scene=t>>5, h) computes g2[h] = W2[h].ghat  (+ w2s rowsums)
//  P2 : thread = pair (j,k): wp,hp accumulated over 32 h from b128 LDS reads;
//       softmax via shfl_xor over the 32-lane group; 5-lane row-sum epilogue.
__global__ __launch_bounds__(BLOCK) void zhat_kernel(
    const float* __restrict__ obs, const float* __restrict__ ghat,
    const float* __restrict__ W1, const float* __restrict__ b1,
    const float* __restrict__ W2, const float* __restrict__ b2,
    float* __restrict__ zbuf, int zstride, int zoff, int B)
{
    __shared__ float s_obs[S8 * 60];        // staged obs tile
    __shared__ float s_gh[S8 * EE];         // staged ghat tile
    __shared__ float s_ab[S8 * 10 * ABS];   // a rows 0..4, b rows 5..9 per scene
    __shared__ float s_g2[S8 * G2S];        // W2 @ ghat per scene
    __shared__ float s_w2s[HH];             // rowsum(W2)
    __shared__ float s_sb2;                 // sum(b2)

    const int tid  = threadIdx.x;
    const int h    = tid & 31;              // owned hidden unit / pair id
    const int sb   = tid >> 5;              // scene-in-block 0..7
    const int blk0 = blockIdx.x * S8;

    // ---- phase 0: stage obs + ghat (coalesced), sb2 ----
    for (int idx = tid; idx < S8 * 60; idx += BLOCK) {
        const int sc = idx / 60, dd = idx - sc * 60;
        int gi = blk0 + sc; if (gi >= B) gi = B - 1;
        s_obs[idx] = obs[(size_t)gi * 60 + dd];
    }
    for (int idx = tid; idx < S8 * EE; idx += BLOCK) {
        const int sc = idx >> 6, e = idx & 63;
        int gi = blk0 + sc; if (gi >= B) gi = B - 1;
        s_gh[idx] = ghat[(size_t)gi * EE + e];
    }
    if (tid == 0) {
        float s = 0.f;
        const float4* p = reinterpret_cast<const float4*>(b2);
        #pragma unroll
        for (int q = 0; q < EE / 4; ++q) { float4 v = p[q]; s += (v.x + v.y) + (v.z + v.w); }
        s_sb2 = s;
    }
    __syncthreads();   // s_obs / s_gh ready

    // ---- phase 1a: a/b rows. entry e = t + 256q -> h fixed, (scene,row) vary ----
    {
        float w1c[24];                       // W1 column h (top 12 | bottom 12)
        #pragma unroll
        for (int dd = 0; dd < 24; ++dd) w1c[dd] = W1[dd * HH + h];   // coalesced
        const float b1h = b1[h];
        #pragma unroll 2
        for (int q = 0; q < 10; ++q) {
            const int rs    = sb + S8 * q;        // 0..79
            const int scene = rs / 10;
            const int row   = rs - scene * 10;    // 0..4 = a, 5..9 = b
            const int jr    = (row < 5) ? row : row - 5;
            const float* op = &s_obs[scene * 60 + jr * DD];
            float accA = b1h, accB = 0.f;
            #pragma unroll
            for (int c = 0; c < 3; ++c) {
                const float4 o4 = *reinterpret_cast<const float4*>(op + 4 * c);
                accA += (o4.x * w1c[4*c+0] + o4.y * w1c[4*c+1])
                      + (o4.z * w1c[4*c+2] + o4.w * w1c[4*c+3]);
                accB += (o4.x * w1c[12+4*c+0] + o4.y * w1c[12+4*c+1])
                      + (o4.z * w1c[12+4*c+2] + o4.w * w1c[12+4*c+3]);
            }
            s_ab[(scene * 10 + row) * ABS + h] = (row < 5) ? accA : accB;
        }
    }

    // ---- phase 1b: g2[sb][h] = W2[h,:] . ghat_sb ; w2s once (sb==0) ----
    {
        const float4* w2r = reinterpret_cast<const float4*>(W2 + h * EE);   // L1-hot
        const float4* ghr = reinterpret_cast<const float4*>(&s_gh[sb * EE]);
        float g2 = 0.f, ws = 0.f;
        #pragma unroll
        for (int ec = 0; ec < EE / 4; ++ec) {
            const float4 wv = w2r[ec];
            const float4 gv = ghr[ec];
            g2 += (wv.x * gv.x + wv.y * gv.y) + (wv.z * gv.z + wv.w * gv.w);
            ws += (wv.x + wv.y) + (wv.z + wv.w);
        }
        s_g2[sb * G2S + h] = g2;
        if (sb == 0) s_w2s[h] = ws;
    }
    __syncthreads();   // s_ab / s_g2 / s_w2s ready

    // ---- phase 2: pair thread (j,k) over 32 h; tiny state ----
    const int j5 = h / 5, k5 = h - j5 * 5;       // j5<=6 for idle lanes (rows valid)
    const float* arow = &s_ab[(sb * 10 + j5) * ABS];
    const float* brow = &s_ab[(sb * 10 + 5 + k5) * ABS];
    const float* g2p  = &s_g2[sb * G2S];
    float wp = (h < 25) ? 0.f : -1e30f;          // idle pair lanes -> exp = 0
    float hp = 0.f;
    #pragma unroll
    for (int h4 = 0; h4 < 8; ++h4) {
        const float4 a4 = *reinterpret_cast<const float4*>(arow + 4 * h4);
        const float4 b4 = *reinterpret_cast<const float4*>(brow + 4 * h4);
        const float4 g4 = *reinterpret_cast<const float4*>(g2p + 4 * h4);
        const float4 w4 = *reinterpret_cast<const float4*>(&s_w2s[4 * h4]);
        float hv;
        hv = fmaxf(a4.x + b4.x, 0.f); wp += hv * g4.x; hp += hv * w4.x;
        hv = fmaxf(a4.y + b4.y, 0.f); wp += hv * g4.y; hp += hv * w4.y;
        hv = fmaxf(a4.z + b4.z, 0.f); wp += hv * g4.z; hp += hv * w4.z;
        hv = fmaxf(a4.w + b4.w, 0.f); wp += hv * g4.w; hp += hv * w4.w;
    }

    // ---- softmax over the 32-lane scene group ----
    float m = wp;
    m = fmaxf(m, __shfl_xor(m, 1));
    m = fmaxf(m, __shfl_xor(m, 2));
    m = fmaxf(m, __shfl_xor(m, 4));
    m = fmaxf(m, __shfl_xor(m, 8));
    m = fmaxf(m, __shfl_xor(m, 16));
    const float e = __expf(wp - m);              // 0 for idle lanes
    float l = e;
    l += __shfl_xor(l, 1);
    l += __shfl_xor(l, 2);
    l += __shfl_xor(l, 4);
    l += __shfl_xor(l, 8);
    l += __shfl_xor(l, 16);
    const float c = e * (hp + s_sb2);            // e * Zsum(j,k)

    // ---- row-sum over k via 5 epilogue shfls; lanes h<5 write zhat ----
    const int lane  = tid & 63;
    const int sbase = lane & 32;                 // scene base within wave
    const int jj    = (h < 5) ? h : 0;
    float z = 0.f;
    #pragma unroll
    for (int k = 0; k < 5; ++k)
        z += __shfl(c, sbase + jj * 5 + k);
    const int isc = blk0 + sb;
    if (h < 5 && isc < B)
        zbuf[(size_t)isc * zstride + zoff + h] = z / l;
}

// ---------------- kernel B: assemble output (proven R3 path) ----------------
__global__ __launch_bounds__(BLOCK) void assemble_kernel(
    const float* __restrict__ obs, const float* __restrict__ ghat,
    const float* __restrict__ zbuf, int zstride, int zoff,
    float* __restrict__ out, int B)
{
    __shared__ float s_obs[TILE * NB * DD];  // 3840 floats
    __shared__ float s_gh[TILE * EE];        // 4096 floats
    __shared__ float s_zh[TILE * NB];        // 320 floats

    const int tid = threadIdx.x;
    const int r0 = blockIdx.x * TILE;
    const int rows = (B - r0 < TILE) ? (B - r0) : TILE;

    for (int t = tid; t < rows * NB * DD; t += BLOCK)
        s_obs[t] = obs[(size_t)r0 * NB * DD + t];
    for (int t = tid; t < rows * EE; t += BLOCK)
        s_gh[t] = ghat[(size_t)r0 * EE + t];
    for (int t = tid; t < rows * NB; t += BLOCK) {
        const int row = t / NB, k = t - row * NB;
        s_zh[t] = zbuf[(size_t)(r0 + row) * zstride + zoff + k];
    }
    __syncthreads();

    const size_t base = (size_t)r0 * OUTW;
    for (int t = tid; t < rows * OUTW; t += BLOCK) {
        const int il = t / OUTW;
        const int r  = t - il * OUTW;
        const int j  = r / ROW;
        const int rr = r - j * ROW;
        float v;
        if (rr < DD)           v = s_obs[il * NB * DD + j * DD + rr];
        else if (rr < DD + EE) v = s_gh[il * EE + (rr - DD)];
        else                   v = s_zh[il * NB + (rr - (DD + EE))];
        out[base + t] = v;
    }
}

extern "C" void kernel_launch(void* const* d_in, const int* in_sizes, int n_in,
                              void* d_out, int out_size, void* d_ws, size_t ws_size,
                              hipStream_t stream) {
    const float* obs  = (const float*)d_in[0];
    const float* ghat = (const float*)d_in[1];
    const float* W1   = (const float*)d_in[2];
    const float* b1   = (const float*)d_in[3];
    const float* W2   = (const float*)d_in[4];
    const float* b2   = (const float*)d_in[5];
    float* out = (float*)d_out;

    const int B = in_sizes[0] / (NB * DD);

    // zhat scratch: d_ws if large enough, else stash in last 5 floats of each
    // output row (assemble reads its tile's stash before overwriting it).
    float* zbuf; int zstride, zoff;
    if (ws_size >= (size_t)B * NB * sizeof(float)) {
        zbuf = (float*)d_ws; zstride = NB;   zoff = 0;
    } else {
        zbuf = out;          zstride = OUTW; zoff = OUTW - NB;
    }

    const int gridA = (B + S8 - 1) / S8;
    hipLaunchKernelGGL(zhat_kernel, dim3(gridA), dim3(BLOCK), 0, stream,
                       obs, ghat, W1, b1, W2, b2, zbuf, zstride, zoff, B);

    const int gridB = (B + TILE - 1) / TILE;
    hipLaunchKernelGGL(assemble_kernel, dim3(gridB), dim3(BLOCK), 0, stream,
                       obs, ghat, zbuf, zstride, zoff, out, B);
}

// Round 13
// 165.830 us; speedup vs baseline: 1.6161x; 1.4216x over previous
//
#include <hip/hip_runtime.h>

#define BLOCK 256
#define NB 5      // objects per scene
#define DD 12     // per-object feature dim
#define EE 64     // goal embedding dim
#define HH 32     // F1 hidden dim
#define ROW 81    // D + E + N
#define OUTW 405  // N * ROW
#define TILE 64   // rows per block in assemble kernel
#define BPB 128   // batches per block (2 threads/batch, lane-pair)
#define W1P 28    // padded W1^T row stride (112B: 16B-aligned rows)

// ---------------- kernel A: compute zhat[B,5], 2 threads per scene ----------------
// Lanes 2m/2m+1 share a scene; lane parity picks the 16-hidden-unit half.
// Single pass accumulates w+hw for own half; halves combined via shfl_xor(1)
// (DPP quad-swap: VALU speed). GEMV over all 32 h with wave-uniform W2 s_loads,
// own half parked in LDS (same-thread readback, no barrier needed).
// Phase order + unroll-1 h-loop chosen to cap live VGPRs (~142 -> 3 waves/SIMD).
__global__ __launch_bounds__(BLOCK) void zhat_kernel(
    const float* __restrict__ obs, const float* __restrict__ ghat,
    const float* __restrict__ W1, const float* __restrict__ b1,
    const float* __restrict__ W2, const float* __restrict__ b2,
    float* __restrict__ zbuf, int zstride, int zoff, int B)
{
    __shared__ float s_W1t[HH * W1P];   // W1^T [h][d<24]
    __shared__ float s_b1[HH];
    __shared__ float s_w2s[HH];         // rowsum(W2)
    __shared__ float s_sb2;             // sum(b2)
    __shared__ float s_g2[BLOCK * 17];  // per-thread own-half g2 park

    const int tid = threadIdx.x;

    // ---- stage W1^T (coalesced read, linearized write), b1, w2s, sb2 ----
    for (int idx = tid; idx < 2 * DD * HH; idx += BLOCK) {
        const int h = idx & (HH - 1);       // idx = d*32 + h
        const int d = idx >> 5;
        s_W1t[h * W1P + d] = W1[idx];
    }
    if (tid < HH) {
        s_b1[tid] = b1[tid];
        float s = 0.f;
        const float4* p = reinterpret_cast<const float4*>(W2 + tid * EE);
        #pragma unroll
        for (int q = 0; q < EE / 4; ++q) { float4 v = p[q]; s += (v.x + v.y) + (v.z + v.w); }
        s_w2s[tid] = s;
    } else if (tid == HH) {
        float s = 0.f;
        #pragma unroll
        for (int e = 0; e < EE; ++e) s += b2[e];
        s_sb2 = s;
    }

    const int lane = tid & 63;
    const int par  = lane & 1;                        // h-half selector
    const int slot = (tid >> 6) * 32 + (lane >> 1);   // scene slot 0..127
    int i = blockIdx.x * BPB + slot;
    const bool act = (i < B);
    const int ic = act ? i : (B - 1);                 // clamp loads; store guarded

    // ---- GEMV: g2[h] = W2[h,:] . ghat_i, all 32 h (uniform W2 -> s_load);
    //      park own half in LDS (read back by same thread: no barrier) ----
    {
        float g2[HH];
        #pragma unroll
        for (int h = 0; h < HH; ++h) g2[h] = 0.f;
        const float* grow = ghat + (size_t)ic * EE;
        #pragma unroll 1
        for (int ec = 0; ec < 4; ++ec) {
            float gc[16];
            const float4* gp = reinterpret_cast<const float4*>(grow + ec * 16);
            #pragma unroll
            for (int q = 0; q < 4; ++q) {
                float4 v = gp[q];
                gc[4*q+0] = v.x; gc[4*q+1] = v.y; gc[4*q+2] = v.z; gc[4*q+3] = v.w;
            }
            #pragma unroll
            for (int q = 0; q < 16; ++q) {
                #pragma unroll
                for (int h = 0; h < HH; ++h)
                    g2[h] += gc[q] * W2[h * EE + ec * 16 + q];   // SGPR-operand FMA
            }
        }
        if (par == 0) {
            #pragma unroll
            for (int hp = 0; hp < 16; ++hp) s_g2[tid * 17 + hp] = g2[hp];
        } else {
            #pragma unroll
            for (int hp = 0; hp < 16; ++hp) s_g2[tid * 17 + hp] = g2[16 + hp];
        }
    }

    // ---- obs row (60 floats) AFTER GEMV: keeps GEMV-phase pressure low ----
    float o[NB * DD];
    {
        const float4* p = reinterpret_cast<const float4*>(obs + (size_t)ic * (NB * DD));
        #pragma unroll
        for (int q = 0; q < NB * DD / 4; ++q) {
            float4 v = p[q];
            o[4*q+0] = v.x; o[4*q+1] = v.y; o[4*q+2] = v.z; o[4*q+3] = v.w;
        }
    }
    __syncthreads();   // publishes s_W1t / s_b1 / s_w2s / s_sb2

    // ---- single pass over my 16 h: accumulate w (logits) + hw ----
    float w[NB * NB], hw[NB * NB];
    #pragma unroll
    for (int q = 0; q < NB * NB; ++q) { w[q] = 0.f; hw[q] = 0.f; }

    const int hbase = par * 16;
    #pragma unroll 1
    for (int hp = 0; hp < 16; ++hp) {
        const int h = hbase + hp;                 // 2 distinct per wave -> broadcast
        const float* w1r = &s_W1t[h * W1P];
        const float g2v = s_g2[tid * 17 + hp];
        const float w2v = s_w2s[h];
        const float b1h = s_b1[h];

        float a[NB];
        {   // top half: 3 f4 loads then 60 FMA (small live window)
            const float4 t0 = *reinterpret_cast<const float4*>(w1r + 0);
            const float4 t1 = *reinterpret_cast<const float4*>(w1r + 4);
            const float4 t2 = *reinterpret_cast<const float4*>(w1r + 8);
            #pragma unroll
            for (int j = 0; j < NB; ++j) {
                const float* oj = &o[j * DD];
                a[j] = b1h
                     + ((oj[0]*t0.x + oj[1]*t0.y) + (oj[2]*t0.z + oj[3]*t0.w))
                     + ((oj[4]*t1.x + oj[5]*t1.y) + (oj[6]*t1.z + oj[7]*t1.w))
                     + ((oj[8]*t2.x + oj[9]*t2.y) + (oj[10]*t2.z + oj[11]*t2.w));
            }
        }
        float bb[NB];
        {   // bottom half
            const float4 u0 = *reinterpret_cast<const float4*>(w1r + DD + 0);
            const float4 u1 = *reinterpret_cast<const float4*>(w1r + DD + 4);
            const float4 u2 = *reinterpret_cast<const float4*>(w1r + DD + 8);
            #pragma unroll
            for (int j = 0; j < NB; ++j) {
                const float* oj = &o[j * DD];
                bb[j] = ((oj[0]*u0.x + oj[1]*u0.y) + (oj[2]*u0.z + oj[3]*u0.w))
                      + ((oj[4]*u1.x + oj[5]*u1.y) + (oj[6]*u1.z + oj[7]*u1.w))
                      + ((oj[8]*u2.x + oj[9]*u2.y) + (oj[10]*u2.z + oj[11]*u2.w));
            }
        }
        #pragma unroll
        for (int j = 0; j < NB; ++j) {
            #pragma unroll
            for (int k = 0; k < NB; ++k) {
                const float hv = fmaxf(a[j] + bb[k], 0.f);
                w[j*NB + k]  += hv * g2v;
                hw[j*NB + k] += hv * w2v;
            }
        }
    }

    // ---- combine h-halves with paired lane (DPP quad-swap, VALU speed) ----
    #pragma unroll
    for (int q = 0; q < NB * NB; ++q) {
        w[q]  += __shfl_xor(w[q], 1);
        hw[q] += __shfl_xor(hw[q], 1);
    }

    // ---- softmax over 25 pairs (redundant in both lanes; identical) ----
    float m = w[0];
    #pragma unroll
    for (int q = 1; q < NB * NB; ++q) m = fmaxf(m, w[q]);
    float racc[NB], zacc[NB];
    float l = 0.f;
    #pragma unroll
    for (int j = 0; j < NB; ++j) {
        float r = 0.f, z = 0.f;
        #pragma unroll
        for (int k = 0; k < NB; ++k) {
            const float e = __expf(w[j*NB + k] - m);
            r += e;
            z += e * hw[j*NB + k];
        }
        racc[j] = r; zacc[j] = z; l += r;
    }

    if (act && par == 0) {
        const float invl = 1.f / l;
        const float sb2 = s_sb2;
        float* zr = zbuf + (size_t)i * zstride + zoff;
        #pragma unroll
        for (int j = 0; j < NB; ++j)
            zr[j] = (zacc[j] + sb2 * racc[j]) * invl;
    }
}

// ---------------- kernel B: assemble output (proven R3 path) ----------------
__global__ __launch_bounds__(BLOCK) void assemble_kernel(
    const float* __restrict__ obs, const float* __restrict__ ghat,
    const float* __restrict__ zbuf, int zstride, int zoff,
    float* __restrict__ out, int B)
{
    __shared__ float s_obs[TILE * NB * DD];  // 3840 floats
    __shared__ float s_gh[TILE * EE];        // 4096 floats
    __shared__ float s_zh[TILE * NB];        // 320 floats

    const int tid = threadIdx.x;
    const int r0 = blockIdx.x * TILE;
    const int rows = (B - r0 < TILE) ? (B - r0) : TILE;

    for (int t = tid; t < rows * NB * DD; t += BLOCK)
        s_obs[t] = obs[(size_t)r0 * NB * DD + t];
    for (int t = tid; t < rows * EE; t += BLOCK)
        s_gh[t] = ghat[(size_t)r0 * EE + t];
    for (int t = tid; t < rows * NB; t += BLOCK) {
        const int row = t / NB, k = t - row * NB;
        s_zh[t] = zbuf[(size_t)(r0 + row) * zstride + zoff + k];
    }
    __syncthreads();

    const size_t base = (size_t)r0 * OUTW;
    for (int t = tid; t < rows * OUTW; t += BLOCK) {
        const int il = t / OUTW;
        const int r  = t - il * OUTW;
        const int j  = r / ROW;
        const int rr = r - j * ROW;
        float v;
        if (rr < DD)           v = s_obs[il * NB * DD + j * DD + rr];
        else if (rr < DD + EE) v = s_gh[il * EE + (rr - DD)];
        else                   v = s_zh[il * NB + (rr - (DD + EE))];
        out[base + t] = v;
    }
}

extern "C" void kernel_launch(void* const* d_in, const int* in_sizes, int n_in,
                              void* d_out, int out_size, void* d_ws, size_t ws_size,
                              hipStream_t stream) {
    const float* obs  = (const float*)d_in[0];
    const float* ghat = (const float*)d_in[1];
    const float* W1   = (const float*)d_in[2];
    const float* b1   = (const float*)d_in[3];
    const float* W2   = (const float*)d_in[4];
    const float* b2   = (const float*)d_in[5];
    float* out = (float*)d_out;

    const int B = in_sizes[0] / (NB * DD);

    // zhat scratch: d_ws if large enough, else stash in last 5 floats of each
    // output row (assemble reads its tile's stash before overwriting it).
    float* zbuf; int zstride, zoff;
    if (ws_size >= (size_t)B * NB * sizeof(float)) {
        zbuf = (float*)d_ws; zstride = NB;   zoff = 0;
    } else {
        zbuf = out;          zstride = OUTW; zoff = OUTW - NB;
    }

    const int gridA = (B + BPB - 1) / BPB;
    hipLaunchKernelGGL(zhat_kernel, dim3(gridA), dim3(BLOCK), 0, stream,
                       obs, ghat, W1, b1, W2, b2, zbuf, zstride, zoff, B);

    const int gridB = (B + TILE - 1) / TILE;
    hipLaunchKernelGGL(assemble_kernel, dim3(gridB), dim3(BLOCK), 0, stream,
                       obs, ghat, zbuf, zstride, zoff, out, B);
}